// Round 19
// baseline (159.746 us; speedup 1.0000x reference)
//
#include <hip/hip_runtime.h>
#include <hip/hip_bf16.h>
#include <math.h>

#define TSEQ 2048
#define NHID 1024

typedef float f32x4 __attribute__((ext_vector_type(4)));
typedef __bf16 bf16x8 __attribute__((ext_vector_type(8)));

static __device__ __forceinline__ unsigned short f2bf(float f) {
  unsigned u = __float_as_uint(f);
  u += 0x7fffu + ((u >> 16) & 1u);
  return (unsigned short)(u >> 16);
}
static __device__ __forceinline__ float bf2f(unsigned short h) {
  return __uint_as_float(((unsigned)h) << 16);
}

#define GLDS16(g, l) __builtin_amdgcn_global_load_lds( \
    (const __attribute__((address_space(1))) unsigned int*)(g), \
    (__attribute__((address_space(3))) unsigned int*)(l), 16, 0, 0)

// ------- transpose 4x 1024x1024 f32 (K,N) -> bf16 (N,K); z=4 slice packs Wb|Wm -------
__global__ __launch_bounds__(256) void transpose_all_kernel(
    const float* __restrict__ Wq, const float* __restrict__ Wk,
    const float* __restrict__ Wv, const float* __restrict__ Wo,
    const float* __restrict__ Wb, const float* __restrict__ Wm,
    unsigned short* __restrict__ Wqkvt, unsigned short* __restrict__ Wto,
    float* __restrict__ Wtf) {
  int m = blockIdx.z;
  int tx = threadIdx.x, ty = threadIdx.y;
  if (m == 4) {
    int blk = blockIdx.y * 32 + blockIdx.x;
    if (blk >= 160) return;
    int id = blk * 256 + ty * 32 + tx;
    int o = id >> 10, i = id & 1023;
    Wtf[id] = (o < 8) ? Wb[i * 8 + o] : Wm[i * 32 + (o - 8)];
    return;
  }
  __shared__ float tile[32][33];
  const float* W;
  unsigned short* Wt;
  if (m == 0)      { W = Wq; Wt = Wqkvt; }
  else if (m == 1) { W = Wk; Wt = Wqkvt + 1024 * 1024; }
  else if (m == 2) { W = Wv; Wt = Wqkvt + 2 * 1024 * 1024; }
  else             { W = Wo; Wt = Wto; }
  int bx = blockIdx.x * 32;
  int by = blockIdx.y * 32;
#pragma unroll
  for (int i = 0; i < 32; i += 8)
    tile[ty + i][tx] = W[(size_t)(by + ty + i) * NHID + bx + tx];
  __syncthreads();
#pragma unroll
  for (int i = 0; i < 32; i += 8)
    Wt[(size_t)(bx + ty + i) * NHID + by + tx] = f2bf(tile[tx][ty + i]);
}

// ------------- bf16 MFMA GEMM, 3-buffer LDS + counted vmcnt(8) (proven R8) -------------
// MODE 0: fused QKV (Bt 3072 rows, K=1024, NT=32); cols<2048 elu+1; bf16 out; XCD swizzle
// MODE 1: Wo split-K=4 (K=256 per z, NT=8); bf16 partial to Pbase + z*4096*1024
template <int MODE>
__global__ __launch_bounds__(256) void gemm_pipe_kernel(
    const unsigned short* __restrict__ A, const unsigned short* __restrict__ Bt,
    unsigned short* __restrict__ Oq, unsigned short* __restrict__ Ok,
    unsigned short* __restrict__ Ov, unsigned short* __restrict__ Pbase) {
  __shared__ __align__(16) unsigned short As[3 * 4096];
  __shared__ __align__(16) unsigned short Bs[3 * 4096];
  const int tid = threadIdx.x;
  const int lane = tid & 63;
  const int wave = tid >> 6;
  const int wr = wave >> 1, wc = wave & 1;
  int bxx = blockIdx.x, byy = blockIdx.y;
  if (MODE == 0) {
    // bijective XCD swizzle (nbxy = 24*32 = 768, %8 == 0)
    const int nbxy = gridDim.x * gridDim.y;
    const int lin = byy * gridDim.x + bxx;
    const int swz = (lin & 7) * (nbxy >> 3) + (lin >> 3);
    bxx = swz % gridDim.x;
    byy = swz / gridDim.x;
  }
  const int rowBase = byy * 128;
  const int colBase = bxx * 128;
  const int NT = (MODE == 0) ? 32 : 8;
  const int kOff = (MODE == 0) ? 0 : blockIdx.z * 256;

  const int c0 = wave * 128 + lane;
  const int c1 = c0 + 64;
  const int r0 = c0 >> 2, kc0 = (c0 & 3) ^ ((r0 >> 1) & 3);
  const int r1 = c1 >> 2, kc1 = (c1 & 3) ^ ((r1 >> 1) & 3);
  const unsigned short* gA0 = A + (size_t)(rowBase + r0) * 1024 + kOff + kc0 * 8;
  const unsigned short* gA1 = A + (size_t)(rowBase + r1) * 1024 + kOff + kc1 * 8;
  const unsigned short* gB0 = Bt + (size_t)(colBase + r0) * 1024 + kOff + kc0 * 8;
  const unsigned short* gB1 = Bt + (size_t)(colBase + r1) * 1024 + kOff + kc1 * 8;
  const int wofs = wave * 1024;

  const int kq = lane >> 4;
  const int r16 = lane & 15;

  f32x4 acc[4][4] = {};

#define STAGE(buf, k0)                                       \
  do {                                                       \
    GLDS16(gA0 + (k0), &As[(buf) * 4096 + wofs]);            \
    GLDS16(gA1 + (k0), &As[(buf) * 4096 + wofs + 512]);      \
    GLDS16(gB0 + (k0), &Bs[(buf) * 4096 + wofs]);            \
    GLDS16(gB1 + (k0), &Bs[(buf) * 4096 + wofs + 512]);      \
  } while (0)

  STAGE(0, 0);
  STAGE(1, 32);
  int cur = 0, stg = 2;
  for (int t = 0; t < NT; ++t) {
    if (t < NT - 2) {
      STAGE(stg, (t + 2) * 32);
      asm volatile("s_waitcnt vmcnt(8)" ::: "memory");
    } else if (t == NT - 2) {
      asm volatile("s_waitcnt vmcnt(4)" ::: "memory");
    } else {
      asm volatile("s_waitcnt vmcnt(0)" ::: "memory");
    }
    __builtin_amdgcn_s_barrier();
    asm volatile("" ::: "memory");
    const unsigned short* Ac = &As[cur * 4096];
    const unsigned short* Bc = &Bs[cur * 4096];
    bf16x8 af[4], bfr[4];
#pragma unroll
    for (int m = 0; m < 4; ++m) {
      int row = wr * 64 + m * 16 + r16;
      af[m] = *(const bf16x8*)(Ac + row * 32 + (kq ^ ((row >> 1) & 3)) * 8);
      int colr = wc * 64 + m * 16 + r16;
      bfr[m] = *(const bf16x8*)(Bc + colr * 32 + (kq ^ ((colr >> 1) & 3)) * 8);
    }
#pragma unroll
    for (int m = 0; m < 4; ++m)
#pragma unroll
      for (int n = 0; n < 4; ++n)
        acc[m][n] = __builtin_amdgcn_mfma_f32_16x16x32_bf16(af[m], bfr[n], acc[m][n], 0, 0, 0);
    asm volatile("" ::: "memory");
    __builtin_amdgcn_s_barrier();
    asm volatile("" ::: "memory");
    cur = (cur == 2) ? 0 : cur + 1;
    stg = (stg == 2) ? 0 : stg + 1;
  }
#undef STAGE

  const int r4 = (lane >> 4) * 4;
  if (MODE == 1) {
    unsigned short* P = Pbase + (size_t)blockIdx.z * 4096 * 1024;
#pragma unroll
    for (int m = 0; m < 4; ++m)
#pragma unroll
      for (int n = 0; n < 4; ++n) {
        int col = colBase + wc * 64 + n * 16 + r16;
#pragma unroll
        for (int j = 0; j < 4; ++j) {
          int row = rowBase + wr * 64 + m * 16 + r4 + j;
          P[(size_t)row * 1024 + col] = f2bf(acc[m][n][j]);
        }
      }
  } else {
    unsigned short* outp;
    int cb;
    bool elu;
    if (colBase < 1024)      { outp = Oq; cb = colBase;        elu = true;  }
    else if (colBase < 2048) { outp = Ok; cb = colBase - 1024; elu = true;  }
    else                     { outp = Ov; cb = colBase - 2048; elu = false; }
#pragma unroll
    for (int m = 0; m < 4; ++m)
#pragma unroll
      for (int n = 0; n < 4; ++n) {
        int col = cb + wc * 64 + n * 16 + r16;
#pragma unroll
        for (int j = 0; j < 4; ++j) {
          int row = rowBase + wr * 64 + m * 16 + r4 + j;
          float v = acc[m][n][j];
          if (elu) v = (v > 0.f) ? (v + 1.f) : expf(v);
          outp[(size_t)row * 1024 + col] = f2bf(v);
        }
      }
  }
}

// ------------- per-(b,t) decay/softmax weights, 8 rows/block + x cast -------------
__global__ __launch_bounds__(256) void rw8_kernel(const float* __restrict__ x,
    const float* __restrict__ Wt, const float* __restrict__ bb,
    const float* __restrict__ bm, const float* __restrict__ base_logit,
    float* __restrict__ R, float* __restrict__ Wsm,
    unsigned short* __restrict__ Xb) {
  __shared__ float xs[8][1024];
  __shared__ float outs[8][40];
  int row0 = blockIdx.x * 8;
  int tid = threadIdx.x;
#pragma unroll
  for (int r = 0; r < 8; ++r) {
    float4 xv = *(const float4*)(x + (size_t)(row0 + r) * 1024 + tid * 4);
    *(float4*)(&xs[r][tid * 4]) = xv;
    ushort4 xo;
    xo.x = f2bf(xv.x); xo.y = f2bf(xv.y); xo.z = f2bf(xv.z); xo.w = f2bf(xv.w);
    *(ushort4*)(Xb + (size_t)(row0 + r) * 1024 + tid * 4) = xo;
  }
  __syncthreads();
  int wave = tid >> 6, lane = tid & 63;
  for (int o = wave; o < 40; o += 4) {
    const float* wr = Wt + o * 1024;
    float w[16];
#pragma unroll
    for (int it = 0; it < 16; ++it) w[it] = wr[it * 64 + lane];
#pragma unroll
    for (int r = 0; r < 8; ++r) {
      float sum = 0.f;
#pragma unroll
      for (int it = 0; it < 16; ++it) sum += xs[r][it * 64 + lane] * w[it];
#pragma unroll
      for (int off = 32; off > 0; off >>= 1) sum += __shfl_down(sum, off);
      if (lane == 0) outs[r][o] = sum;
    }
  }
  __syncthreads();
  {
    int r = tid >> 5, j = tid & 31;
    int row = row0 + r;
    int h = j >> 2;
    float beta = 1.f / (1.f + expf(-(outs[r][h] + bb[h])));
    float br = 1.f / (1.f + expf(-base_logit[j]));
    float rr = fminf(fmaxf(beta * br, 0.f), 0.999995f);
    float mval = outs[r][8 + j] + bm[j];
    float mx = fmaxf(mval, __shfl_xor(mval, 1));
    mx = fmaxf(mx, __shfl_xor(mx, 2));
    float ex = expf(mval - mx);
    float ssum = ex + __shfl_xor(ex, 1);
    ssum += __shfl_xor(ssum, 2);
    R[(size_t)row * 32 + j] = rr;
    Wsm[(size_t)row * 32 + j] = ex / ssum;
  }
}

// KT/VT LDS layout: row d (256B), 16B slot phys = (t>>3) ^ (d&7) ^ ((d>>3)&7), elem t&7.
#define KV_SLOT(j, d) (((j) ^ ((d) & 7) ^ (((d) >> 3) & 7)) << 4)

// --------- kernel A: per (bh,chunk): fused decay-scan + local attention + U^T ---------
// UT / Olb use fragment-linear tile layout: idx = wave*2048 + (f*4+jj)*64 + lane
__global__ __launch_bounds__(512) void chunkA_kernel(
    const unsigned short* __restrict__ Qb, const unsigned short* __restrict__ Kb,
    const unsigned short* __restrict__ Vb,
    const float* __restrict__ R, const float* __restrict__ Wsm,
    const float* __restrict__ mask,
    float* __restrict__ WAg, float* __restrict__ AC,
    unsigned short* __restrict__ Olb, unsigned short* __restrict__ UT) {
  __shared__ __align__(16) char KTl[32768];
  __shared__ __align__(16) char VTl[32768];
  __shared__ __align__(16) char Pl[32768];
  __shared__ __align__(16) float WAl[128][4];
  __shared__ __align__(16) float IAl[128][4];
  __shared__ float DUl[4][128];

  int wg = blockIdx.x;
  int bh = wg >> 4, c = wg & 15;
  int b = bh >> 3, h = bh & 7;
  int t0 = c * 128;
  int tid = threadIdx.x;
  int lane = tid & 63, wave = tid >> 6;
  int wbase = wave * 16;
  int l15 = lane & 15, lq = lane >> 4;

  const size_t qkvbase = ((size_t)b * TSEQ + t0) * 1024 + h * 128;

  for (int it = 0; it < 2; ++it) {
    int ci = tid + it * 512;
    int t = (ci >> 4) * 2, s = ci & 15;
    bf16x8 k0 = *(const bf16x8*)(Kb + qkvbase + (size_t)t * 1024 + s * 8);
    bf16x8 k1 = *(const bf16x8*)(Kb + qkvbase + (size_t)(t + 1) * 1024 + s * 8);
    bf16x8 v0 = *(const bf16x8*)(Vb + qkvbase + (size_t)t * 1024 + s * 8);
    bf16x8 v1 = *(const bf16x8*)(Vb + qkvbase + (size_t)(t + 1) * 1024 + s * 8);
    const unsigned short* k0u = (const unsigned short*)&k0;
    const unsigned short* k1u = (const unsigned short*)&k1;
    const unsigned short* v0u = (const unsigned short*)&v0;
    const unsigned short* v1u = (const unsigned short*)&v1;
#pragma unroll
    for (int e = 0; e < 8; ++e) {
      int d = s * 8 + e;
      int off = d * 256 + (((t >> 3) ^ (d & 7) ^ ((d >> 3) & 7)) << 4) + (t & 7) * 2;
      *(unsigned int*)(KTl + off) = (unsigned)k0u[e] | ((unsigned)k1u[e] << 16);
      *(unsigned int*)(VTl + off) = (unsigned)v0u[e] | ((unsigned)v1u[e] << 16);
    }
  }
  if (wave < 4) {
    int k = wave;
    int rowg = b * TSEQ + t0 + 2 * lane;
    float m0 = mask[rowg], m1 = mask[rowg + 1];
    size_t i0 = (size_t)rowg * 32 + h * 4 + k;
    float rr0 = (m0 > 0.f) ? R[i0] : 1.f;
    float rr1 = (m1 > 0.f) ? R[i0 + 32] : 1.f;
    float incl = rr0 * rr1;
#pragma unroll
    for (int off = 1; off < 64; off <<= 1) {
      float o = __shfl_up(incl, off);
      if (lane >= off) incl *= o;
    }
    float excl = __shfl_up(incl, 1);
    if (lane == 0) excl = 1.f;
    float a0 = fmaxf(excl * rr0, 1e-25f);
    float a1 = fmaxf(a0 * rr1, 1e-25f);
    float aC = __shfl(a1, 63);
    if (lane == 63) AC[(bh * 16 + c) * 4 + k] = a1;
    bool v0 = m0 > 0.f, v1 = m1 > 0.f;
    float w0 = Wsm[i0], w1 = Wsm[i0 + 32];
    float wa0 = v0 ? w0 * a0 : 0.f;
    float wa1 = v1 ? w1 * a1 : 0.f;
    WAl[2 * lane][k] = wa0;
    WAl[2 * lane + 1][k] = wa1;
    IAl[2 * lane][k] = v0 ? 1.f / a0 : 0.f;
    IAl[2 * lane + 1][k] = v1 ? 1.f / a1 : 0.f;
    DUl[k][2 * lane] = v0 ? aC / a0 : 0.f;
    DUl[k][2 * lane + 1] = v1 ? aC / a1 : 0.f;
    WAg[i0] = wa0;
    WAg[i0 + 32] = wa1;
  }
  __syncthreads();

  bf16x8 qf[4];
#pragma unroll
  for (int ds = 0; ds < 4; ++ds)
    qf[ds] = *(const bf16x8*)(Qb + qkvbase + (size_t)(wbase + l15) * 1024 + ds * 32 + lq * 8);
  f32x4 accP[8];
#pragma unroll
  for (int jf = 0; jf < 8; ++jf) {
    f32x4 a = {};
#pragma unroll
    for (int ds = 0; ds < 4; ++ds) {
      bf16x8 kfrag = *(const bf16x8*)(Kb + qkvbase + (size_t)(jf * 16 + l15) * 1024 + ds * 32 + lq * 8);
      a = __builtin_amdgcn_mfma_f32_16x16x32_bf16(qf[ds], kfrag, a, 0, 0, 0);
    }
    accP[jf] = a;
  }

  float4 wa4[4];
#pragma unroll
  for (int jj = 0; jj < 4; ++jj)
    wa4[jj] = *(const float4*)&WAl[wbase + lq * 4 + jj][0];
#pragma unroll
  for (int jf = 0; jf < 8; ++jf) {
    float4 ia4 = *(const float4*)&IAl[jf * 16 + l15][0];
#pragma unroll
    for (int jj = 0; jj < 4; ++jj) {
      int tl = wbase + lq * 4 + jj;
      int jl = jf * 16 + l15;
      float m = 0.f;
      if (jl <= tl)
        m = wa4[jj].x * ia4.x + wa4[jj].y * ia4.y + wa4[jj].z * ia4.z + wa4[jj].w * ia4.w;
      float pv = accP[jf][jj] * m;
      int off = tl * 256 + (((jl >> 3) ^ (tl & 7)) << 4) + (jl & 7) * 2;
      *(unsigned short*)(Pl + off) = f2bf(pv);
    }
  }

  bf16x8 pf[4];
#pragma unroll
  for (int js = 0; js < 4; ++js) {
    int tl = wbase + l15;
    int slot = js * 4 + lq;
    pf[js] = *(const bf16x8*)(Pl + tl * 256 + ((slot ^ (tl & 7)) << 4));
  }
  size_t olb = (size_t)wg * 16384 + wave * 2048 + lane;
#pragma unroll
  for (int dvf = 0; dvf < 8; ++dvf) {
    f32x4 a = {};
    int dv = dvf * 16 + l15;
#pragma unroll
    for (int js = 0; js < 4; ++js) {
      int slot = js * 4 + lq;
      bf16x8 vfrag = *(const bf16x8*)(VTl + dv * 256 + KV_SLOT(slot, dv));
      a = __builtin_amdgcn_mfma_f32_16x16x32_bf16(pf[js], vfrag, a, 0, 0, 0);
    }
#pragma unroll
    for (int jj = 0; jj < 4; ++jj)
      Olb[olb + (dvf * 4 + jj) * 64] = f2bf(a[jj]);
  }

  if (c < 15) {
#pragma unroll 1
    for (int k = 0; k < 4; ++k) {
      f32x4 accU[8] = {};
#pragma unroll 1
      for (int js = 0; js < 4; ++js) {
        int dvr = wbase + l15;
        int slot = js * 4 + lq;
        bf16x8 af = *(const bf16x8*)(VTl + dvr * 256 + KV_SLOT(slot, dvr));
        int j0 = js * 32 + lq * 8;
        bf16x8 afs;
#pragma unroll
        for (int e = 0; e < 8; ++e)
          afs[e] = (__bf16)((float)af[e] * DUl[k][j0 + e]);
#pragma unroll
        for (int dkf = 0; dkf < 8; ++dkf) {
          int dk = dkf * 16 + l15;
          bf16x8 kf = *(const bf16x8*)(KTl + dk * 256 + KV_SLOT(slot, dk));
          accU[dkf] = __builtin_amdgcn_mfma_f32_16x16x32_bf16(afs, kf, accU[dkf], 0, 0, 0);
        }
      }
      size_t ub = (((size_t)bh * 16 + c) * 4 + k) * 16384 + wave * 2048 + lane;
#pragma unroll
      for (int dkf = 0; dkf < 8; ++dkf)
#pragma unroll
        for (int jj = 0; jj < 4; ++jj)
          UT[ub + (dkf * 4 + jj) * 64] = f2bf(accU[dkf][jj]);
    }
  }
}

// --- kernel B: S <- aC*S + U. Reads UT frag-linear (coalesced), writes S0T ROW-MAJOR ---
__global__ __launch_bounds__(256) void chainB_kernel(const unsigned short* __restrict__ UT,
    const float* __restrict__ AC, unsigned short* __restrict__ S0T) {
  int id = blockIdx.x * 256 + threadIdx.x;
  int q = id & 4095;
  int k = (id >> 12) & 3;
  int bh = id >> 14;
  int row = ((q >> 9) << 4) + (((q & 15) >> 2) << 2) + ((q >> 4) & 3);
  int col = (((q >> 6) & 7) << 4) + ((q & 3) << 2);
  size_t rdofs = (size_t)q * 4;
  size_t wrofs = (size_t)row * 128 + col;
  float S0 = 0.f, S1 = 0.f, S2 = 0.f, S3 = 0.f;
#pragma unroll 1
  for (int c = 0; c < 15; ++c) {
    size_t ub = (((size_t)bh * 16 + c) * 4 + k) * 16384 + rdofs;
    ushort4 u = *(const ushort4*)(UT + ub);
    float aC = AC[(bh * 16 + c) * 4 + k];
    S0 = aC * S0 + bf2f(u.x);
    S1 = aC * S1 + bf2f(u.y);
    S2 = aC * S2 + bf2f(u.z);
    S3 = aC * S3 + bf2f(u.w);
    size_t sb = (((size_t)bh * 16 + (c + 1)) * 4 + k) * 16384 + wrofs;
    ushort4 o;
    o.x = f2bf(S0); o.y = f2bf(S1); o.z = f2bf(S2); o.w = f2bf(S3);
    *(ushort4*)(S0T + sb) = o;
  }
}

// --------- kernel C: cross-chunk O += sum_k diag(w*a) Q @ S0^k (R13-fix inner loop) ---------
__global__ __launch_bounds__(512) void chunkC_kernel(const unsigned short* __restrict__ Qb,
    const unsigned short* __restrict__ S0T, const float* __restrict__ WA,
    const unsigned short* __restrict__ Olb, unsigned short* __restrict__ Ob) {
  __shared__ __align__(16) char Sl[32768];
  int wg = blockIdx.x;
  int bh = wg >> 4, c = wg & 15;
  int b = bh >> 3, h = bh & 7;
  int t0 = c * 128;
  int tid = threadIdx.x, lane = tid & 63, wave = tid >> 6;
  int l15 = lane & 15, lq = lane >> 4, wbase = wave * 16;
  size_t qbase = ((size_t)b * TSEQ + t0) * 1024 + h * 128;

  f32x4 accO[8] = {};
  if (c > 0) {
    int tl = wbase + l15;
    size_t so[4];
#pragma unroll
    for (int it = 0; it < 4; ++it) {
      int ci = tid + it * 512;
      int dv = ci >> 4, p = ci & 15;
      so[it] = (size_t)dv * 128 + (size_t)(p ^ (dv & 7)) * 8;
    }
#pragma unroll 1
    for (int k = 0; k < 4; ++k) {
      __syncthreads();
      size_t sb = (((size_t)bh * 16 + c) * 4 + k) * 16384;
      GLDS16(S0T + sb + so[0], (unsigned short*)(Sl + wave * 1024));
      GLDS16(S0T + sb + so[1], (unsigned short*)(Sl + 8192 + wave * 1024));
      GLDS16(S0T + sb + so[2], (unsigned short*)(Sl + 16384 + wave * 1024));
      GLDS16(S0T + sb + so[3], (unsigned short*)(Sl + 24576 + wave * 1024));
      asm volatile("s_waitcnt vmcnt(0)" ::: "memory");
      __syncthreads();
      float sc = WA[((size_t)b * TSEQ + t0 + tl) * 32 + h * 4 + k];
#pragma unroll 1
      for (int ds = 0; ds < 4; ++ds) {
        bf16x8 qf = *(const bf16x8*)(Qb + qbase + (size_t)tl * 1024 + ds * 32 + lq * 8);
        bf16x8 qs;
#pragma unroll
        for (int e = 0; e < 8; ++e) qs[e] = (__bf16)((float)qf[e] * sc);
#pragma unroll
        for (int dvf = 0; dvf < 8; ++dvf) {
          int dv = dvf * 16 + l15;
          int slot = ds * 4 + lq;
          bf16x8 sf = *(const bf16x8*)(Sl + dv * 256 + ((slot ^ (dv & 7)) << 4));
          accO[dvf] = __builtin_amdgcn_mfma_f32_16x16x32_bf16(qs, sf, accO[dvf], 0, 0, 0);
        }
      }
    }
  }
  size_t olb = (size_t)wg * 16384 + wave * 2048 + lane;
#pragma unroll
  for (int dvf = 0; dvf < 8; ++dvf) {
    int dv = dvf * 16 + l15;
#pragma unroll
    for (int jj = 0; jj < 4; ++jj) {
      int tl = wbase + lq * 4 + jj;
      size_t off = ((size_t)b * TSEQ + t0 + tl) * 1024 + h * 128 + dv;
      float ol = bf2f(Olb[olb + (dvf * 4 + jj) * 64]);
      Ob[off] = f2bf(accO[dvf][jj] + ol);
    }
  }
}

// ------- LayerNorm: y = ((P0+P1)+(P2+P3))+bo+x (P bf16), then LN -> f32 out -------
__global__ __launch_bounds__(256) void ln_kernel(const unsigned short* __restrict__ Pbase,
    const float* __restrict__ bo, const float* __restrict__ xres,
    const float* __restrict__ g, const float* __restrict__ bta,
    float* __restrict__ out) {
  int row = blockIdx.x;
  int tid = threadIdx.x;
  int lane = tid & 63, wave = tid >> 6;
  __shared__ float red[8];
  size_t base = (size_t)row * 1024 + tid * 4;
  const size_t PS = (size_t)4096 * 1024;
  ushort4 a = *(const ushort4*)(Pbase + base);
  ushort4 b2 = *(const ushort4*)(Pbase + PS + base);
  ushort4 c2 = *(const ushort4*)(Pbase + 2 * PS + base);
  ushort4 d2 = *(const ushort4*)(Pbase + 3 * PS + base);
  float4 xv = *(const float4*)(xres + base);
  float4 bv = *(const float4*)(bo + tid * 4);
  float4 v;
  v.x = ((bf2f(a.x) + bf2f(b2.x)) + (bf2f(c2.x) + bf2f(d2.x))) + bv.x + xv.x;
  v.y = ((bf2f(a.y) + bf2f(b2.y)) + (bf2f(c2.y) + bf2f(d2.y))) + bv.y + xv.y;
  v.z = ((bf2f(a.z) + bf2f(b2.z)) + (bf2f(c2.z) + bf2f(d2.z))) + bv.z + xv.z;
  v.w = ((bf2f(a.w) + bf2f(b2.w)) + (bf2f(c2.w) + bf2f(d2.w))) + bv.w + xv.w;
  float sum = v.x + v.y + v.z + v.w;
#pragma unroll
  for (int off = 32; off > 0; off >>= 1) sum += __shfl_down(sum, off);
  if (lane == 0) red[wave] = sum;
  __syncthreads();
  float mu = (red[0] + red[1] + red[2] + red[3]) * (1.f / 1024.f);
  float4 d;
  d.x = v.x - mu; d.y = v.y - mu; d.z = v.z - mu; d.w = v.w - mu;
  float sq = d.x * d.x + d.y * d.y + d.z * d.z + d.w * d.w;
#pragma unroll
  for (int off = 32; off > 0; off >>= 1) sq += __shfl_down(sq, off);
  __syncthreads();
  if (lane == 0) red[4 + wave] = sq;
  __syncthreads();
  float var = (red[4] + red[5] + red[6] + red[7]) * (1.f / 1024.f);
  float inv = rsqrtf(var + 1e-5f);
  float4 gg = *(const float4*)(g + tid * 4);
  float4 bb4 = *(const float4*)(bta + tid * 4);
  float4 o;
  o.x = d.x * inv * gg.x + bb4.x;
  o.y = d.y * inv * gg.y + bb4.y;
  o.z = d.z * inv * gg.z + bb4.z;
  o.w = d.w * inv * gg.w + bb4.w;
  *(float4*)(out + (size_t)row * 1024 + tid * 4) = o;
}

extern "C" void kernel_launch(void* const* d_in, const int* in_sizes, int n_in,
                              void* d_out, int out_size, void* d_ws, size_t ws_size,
                              hipStream_t stream) {
  const float* x    = (const float*)d_in[0];
  const float* mask = (const float*)d_in[1];
  const float* Wq   = (const float*)d_in[2];
  const float* Wk   = (const float*)d_in[3];
  const float* Wv   = (const float*)d_in[4];
  const float* Wb   = (const float*)d_in[5];
  const float* bb   = (const float*)d_in[6];
  const float* Wm   = (const float*)d_in[7];
  const float* bm   = (const float*)d_in[8];
  const float* Wo   = (const float*)d_in[9];
  const float* bo   = (const float*)d_in[10];
  const float* base_logit = (const float*)d_in[11];
  const float* ln_g = (const float*)d_in[12];
  const float* ln_b = (const float*)d_in[13];

  char* ws = (char*)d_ws;
  const size_t MB = 1024u * 1024u;
  unsigned short* Xb    = (unsigned short*)(ws + 0);        // 8 MB
  unsigned short* Wqkvt = (unsigned short*)(ws + 8 * MB);   // 6 MB
  unsigned short* Wto   = (unsigned short*)(ws + 14 * MB);  // 2 MB
  float* Rf  = (float*)(ws + 16 * MB);
  float* Wsf = (float*)(ws + 16 * MB + 512 * 1024);
  float* WAf = (float*)(ws + 17 * MB);
  float* ACf = (float*)(ws + 18 * MB);
  float* Wtf = (float*)(ws + 18 * MB + 768 * 1024);
  unsigned short* Qb  = (unsigned short*)(ws + 19 * MB);    // 8 MB
  unsigned short* Kb  = (unsigned short*)(ws + 27 * MB);    // 8 MB
  unsigned short* Vb  = (unsigned short*)(ws + 35 * MB);    // 8 MB
  unsigned short* Olb = (unsigned short*)(ws + 43 * MB);    // 8 MB bf16 (frag-linear)
  unsigned short* Ob  = (unsigned short*)(ws + 51 * MB);    // 8 MB
  unsigned short* UTb = (unsigned short*)(ws + 59 * MB);    // 32 MB (frag-linear)
  unsigned short* S0T = (unsigned short*)(ws + 91 * MB);    // 32 MB (row-major)
  unsigned short* Pp = (unsigned short*)(ws + 59 * MB);     // 4x8 MB bf16 partials (UTb dead)
  if (ws_size < 131 * MB) return;

  dim3 tb(32, 8), tg(32, 32, 5);
  transpose_all_kernel<<<tg, tb, 0, stream>>>(Wq, Wk, Wv, Wo, Wb, Wm, Wqkvt, Wto, Wtf);

  rw8_kernel<<<512, 256, 0, stream>>>(x, Wtf, bb, bm, base_logit, Rf, Wsf, Xb);

  dim3 gqkv(24, 32);
  gemm_pipe_kernel<0><<<gqkv, 256, 0, stream>>>(Xb, Wqkvt, Qb, Kb, Vb, nullptr);

  chunkA_kernel<<<256, 512, 0, stream>>>(Qb, Kb, Vb, Rf, Wsf, mask, WAf, ACf, Olb, UTb);
  chainB_kernel<<<1024, 256, 0, stream>>>(UTb, ACf, S0T);
  chunkC_kernel<<<256, 512, 0, stream>>>(Qb, S0T, WAf, Olb, Ob);

  dim3 gwo(8, 32, 4);
  gemm_pipe_kernel<1><<<gwo, 256, 0, stream>>>(Ob, Wto, nullptr, nullptr, nullptr, Pp);

  ln_kernel<<<4096, 256, 0, stream>>>(Pp, bo, x, ln_g, ln_b, (float*)d_out);
}

// Round 20
// 155.271 us; speedup vs baseline: 1.0288x; 1.0288x over previous
//
#include <hip/hip_runtime.h>
#include <hip/hip_bf16.h>
#include <math.h>

#define TSEQ 2048
#define NHID 1024

typedef float f32x4 __attribute__((ext_vector_type(4)));
typedef __bf16 bf16x8 __attribute__((ext_vector_type(8)));

static __device__ __forceinline__ unsigned short f2bf(float f) {
  unsigned u = __float_as_uint(f);
  u += 0x7fffu + ((u >> 16) & 1u);
  return (unsigned short)(u >> 16);
}
static __device__ __forceinline__ float bf2f(unsigned short h) {
  return __uint_as_float(((unsigned)h) << 16);
}

#define GLDS16(g, l) __builtin_amdgcn_global_load_lds( \
    (const __attribute__((address_space(1))) unsigned int*)(g), \
    (__attribute__((address_space(3))) unsigned int*)(l), 16, 0, 0)

// ------- transpose 4x 1024x1024 f32 (K,N) -> bf16 (N,K); z=4 slice packs Wb|Wm -------
__global__ __launch_bounds__(256) void transpose_all_kernel(
    const float* __restrict__ Wq, const float* __restrict__ Wk,
    const float* __restrict__ Wv, const float* __restrict__ Wo,
    const float* __restrict__ Wb, const float* __restrict__ Wm,
    unsigned short* __restrict__ Wqkvt, unsigned short* __restrict__ Wto,
    float* __restrict__ Wtf) {
  int m = blockIdx.z;
  int tx = threadIdx.x, ty = threadIdx.y;
  if (m == 4) {
    int blk = blockIdx.y * 32 + blockIdx.x;
    if (blk >= 160) return;
    int id = blk * 256 + ty * 32 + tx;
    int o = id >> 10, i = id & 1023;
    Wtf[id] = (o < 8) ? Wb[i * 8 + o] : Wm[i * 32 + (o - 8)];
    return;
  }
  __shared__ float tile[32][33];
  const float* W;
  unsigned short* Wt;
  if (m == 0)      { W = Wq; Wt = Wqkvt; }
  else if (m == 1) { W = Wk; Wt = Wqkvt + 1024 * 1024; }
  else if (m == 2) { W = Wv; Wt = Wqkvt + 2 * 1024 * 1024; }
  else             { W = Wo; Wt = Wto; }
  int bx = blockIdx.x * 32;
  int by = blockIdx.y * 32;
#pragma unroll
  for (int i = 0; i < 32; i += 8)
    tile[ty + i][tx] = W[(size_t)(by + ty + i) * NHID + bx + tx];
  __syncthreads();
#pragma unroll
  for (int i = 0; i < 32; i += 8)
    Wt[(size_t)(bx + ty + i) * NHID + by + tx] = f2bf(tile[tx][ty + i]);
}

// ------------- bf16 MFMA GEMM, 3-buffer LDS + counted vmcnt(8) (proven R8) -------------
// MODE 0: fused QKV (Bt 3072 rows, K=1024, NT=32); cols<2048 elu+1; bf16 out Oq/Ok/Ov
// MODE 1: Wo split-K=2 (K=512 per z, NT=16); bf16 partial to Pbase + z*4096*1024
template <int MODE>
__global__ __launch_bounds__(256) void gemm_pipe_kernel(
    const unsigned short* __restrict__ A, const unsigned short* __restrict__ Bt,
    unsigned short* __restrict__ Oq, unsigned short* __restrict__ Ok,
    unsigned short* __restrict__ Ov, unsigned short* __restrict__ Pbase) {
  __shared__ __align__(16) unsigned short As[3 * 4096];
  __shared__ __align__(16) unsigned short Bs[3 * 4096];
  const int tid = threadIdx.x;
  const int lane = tid & 63;
  const int wave = tid >> 6;
  const int wr = wave >> 1, wc = wave & 1;
  const int rowBase = blockIdx.y * 128;
  const int colBase = blockIdx.x * 128;
  const int NT = (MODE == 0) ? 32 : 16;
  const int kOff = (MODE == 0) ? 0 : blockIdx.z * 512;

  const int c0 = wave * 128 + lane;
  const int c1 = c0 + 64;
  const int r0 = c0 >> 2, kc0 = (c0 & 3) ^ ((r0 >> 1) & 3);
  const int r1 = c1 >> 2, kc1 = (c1 & 3) ^ ((r1 >> 1) & 3);
  const unsigned short* gA0 = A + (size_t)(rowBase + r0) * 1024 + kOff + kc0 * 8;
  const unsigned short* gA1 = A + (size_t)(rowBase + r1) * 1024 + kOff + kc1 * 8;
  const unsigned short* gB0 = Bt + (size_t)(colBase + r0) * 1024 + kOff + kc0 * 8;
  const unsigned short* gB1 = Bt + (size_t)(colBase + r1) * 1024 + kOff + kc1 * 8;
  const int wofs = wave * 1024;

  const int kq = lane >> 4;
  const int r16 = lane & 15;

  f32x4 acc[4][4] = {};

#define STAGE(buf, k0)                                       \
  do {                                                       \
    GLDS16(gA0 + (k0), &As[(buf) * 4096 + wofs]);            \
    GLDS16(gA1 + (k0), &As[(buf) * 4096 + wofs + 512]);      \
    GLDS16(gB0 + (k0), &Bs[(buf) * 4096 + wofs]);            \
    GLDS16(gB1 + (k0), &Bs[(buf) * 4096 + wofs + 512]);      \
  } while (0)

  STAGE(0, 0);
  STAGE(1, 32);
  int cur = 0, stg = 2;
  for (int t = 0; t < NT; ++t) {
    if (t < NT - 2) {
      STAGE(stg, (t + 2) * 32);
      asm volatile("s_waitcnt vmcnt(8)" ::: "memory");
    } else if (t == NT - 2) {
      asm volatile("s_waitcnt vmcnt(4)" ::: "memory");
    } else {
      asm volatile("s_waitcnt vmcnt(0)" ::: "memory");
    }
    __builtin_amdgcn_s_barrier();
    asm volatile("" ::: "memory");
    const unsigned short* Ac = &As[cur * 4096];
    const unsigned short* Bc = &Bs[cur * 4096];
    bf16x8 af[4], bfr[4];
#pragma unroll
    for (int m = 0; m < 4; ++m) {
      int row = wr * 64 + m * 16 + r16;
      af[m] = *(const bf16x8*)(Ac + row * 32 + (kq ^ ((row >> 1) & 3)) * 8);
      int colr = wc * 64 + m * 16 + r16;
      bfr[m] = *(const bf16x8*)(Bc + colr * 32 + (kq ^ ((colr >> 1) & 3)) * 8);
    }
#pragma unroll
    for (int m = 0; m < 4; ++m)
#pragma unroll
      for (int n = 0; n < 4; ++n)
        acc[m][n] = __builtin_amdgcn_mfma_f32_16x16x32_bf16(af[m], bfr[n], acc[m][n], 0, 0, 0);
    asm volatile("" ::: "memory");
    __builtin_amdgcn_s_barrier();
    asm volatile("" ::: "memory");
    cur = (cur == 2) ? 0 : cur + 1;
    stg = (stg == 2) ? 0 : stg + 1;
  }
#undef STAGE

  const int r4 = (lane >> 4) * 4;
  if (MODE == 1) {
    unsigned short* P = Pbase + (size_t)blockIdx.z * 4096 * 1024;
#pragma unroll
    for (int m = 0; m < 4; ++m)
#pragma unroll
      for (int n = 0; n < 4; ++n) {
        int col = colBase + wc * 64 + n * 16 + r16;
#pragma unroll
        for (int j = 0; j < 4; ++j) {
          int row = rowBase + wr * 64 + m * 16 + r4 + j;
          P[(size_t)row * 1024 + col] = f2bf(acc[m][n][j]);
        }
      }
  } else {
    unsigned short* outp;
    int cb;
    bool elu;
    if (colBase < 1024)      { outp = Oq; cb = colBase;        elu = true;  }
    else if (colBase < 2048) { outp = Ok; cb = colBase - 1024; elu = true;  }
    else                     { outp = Ov; cb = colBase - 2048; elu = false; }
#pragma unroll
    for (int m = 0; m < 4; ++m)
#pragma unroll
      for (int n = 0; n < 4; ++n) {
        int col = cb + wc * 64 + n * 16 + r16;
#pragma unroll
        for (int j = 0; j < 4; ++j) {
          int row = rowBase + wr * 64 + m * 16 + r4 + j;
          float v = acc[m][n][j];
          if (elu) v = (v > 0.f) ? (v + 1.f) : expf(v);
          outp[(size_t)row * 1024 + col] = f2bf(v);
        }
      }
  }
}

// ------------- per-(b,t) decay/softmax weights, 8 rows/block + x cast -------------
__global__ __launch_bounds__(256) void rw8_kernel(const float* __restrict__ x,
    const float* __restrict__ Wt, const float* __restrict__ bb,
    const float* __restrict__ bm, const float* __restrict__ base_logit,
    float* __restrict__ R, float* __restrict__ Wsm,
    unsigned short* __restrict__ Xb) {
  __shared__ float xs[8][1024];
  __shared__ float outs[8][40];
  int row0 = blockIdx.x * 8;
  int tid = threadIdx.x;
#pragma unroll
  for (int r = 0; r < 8; ++r) {
    float4 xv = *(const float4*)(x + (size_t)(row0 + r) * 1024 + tid * 4);
    *(float4*)(&xs[r][tid * 4]) = xv;
    ushort4 xo;
    xo.x = f2bf(xv.x); xo.y = f2bf(xv.y); xo.z = f2bf(xv.z); xo.w = f2bf(xv.w);
    *(ushort4*)(Xb + (size_t)(row0 + r) * 1024 + tid * 4) = xo;
  }
  __syncthreads();
  int wave = tid >> 6, lane = tid & 63;
  for (int o = wave; o < 40; o += 4) {
    const float* wr = Wt + o * 1024;
    float w[16];
#pragma unroll
    for (int it = 0; it < 16; ++it) w[it] = wr[it * 64 + lane];
#pragma unroll
    for (int r = 0; r < 8; ++r) {
      float sum = 0.f;
#pragma unroll
      for (int it = 0; it < 16; ++it) sum += xs[r][it * 64 + lane] * w[it];
#pragma unroll
      for (int off = 32; off > 0; off >>= 1) sum += __shfl_down(sum, off);
      if (lane == 0) outs[r][o] = sum;
    }
  }
  __syncthreads();
  {
    int r = tid >> 5, j = tid & 31;
    int row = row0 + r;
    int h = j >> 2;
    float beta = 1.f / (1.f + expf(-(outs[r][h] + bb[h])));
    float br = 1.f / (1.f + expf(-base_logit[j]));
    float rr = fminf(fmaxf(beta * br, 0.f), 0.999995f);
    float mval = outs[r][8 + j] + bm[j];
    float mx = fmaxf(mval, __shfl_xor(mval, 1));
    mx = fmaxf(mx, __shfl_xor(mx, 2));
    float ex = expf(mval - mx);
    float ssum = ex + __shfl_xor(ex, 1);
    ssum += __shfl_xor(ssum, 2);
    R[(size_t)row * 32 + j] = rr;
    Wsm[(size_t)row * 32 + j] = ex / ssum;
  }
}

// KT/VT LDS layout: row d (256B), 16B slot phys = (t>>3) ^ (d&7) ^ ((d>>3)&7), elem t&7.
#define KV_SLOT(j, d) (((j) ^ ((d) & 7) ^ (((d) >> 3) & 7)) << 4)

// --------- kernel A: per (bh,chunk): fused decay-scan + local attention + U^T ---------
// UT / Olb use fragment-linear tile layout: idx = wave*2048 + (f*4+jj)*64 + lane
__global__ __launch_bounds__(512) void chunkA_kernel(
    const unsigned short* __restrict__ Qb, const unsigned short* __restrict__ Kb,
    const unsigned short* __restrict__ Vb,
    const float* __restrict__ R, const float* __restrict__ Wsm,
    const float* __restrict__ mask,
    float* __restrict__ WAg, float* __restrict__ AC,
    unsigned short* __restrict__ Olb, unsigned short* __restrict__ UT) {
  __shared__ __align__(16) char KTl[32768];
  __shared__ __align__(16) char VTl[32768];
  __shared__ __align__(16) char Pl[32768];
  __shared__ __align__(16) float WAl[128][4];
  __shared__ __align__(16) float IAl[128][4];
  __shared__ float DUl[4][128];

  int wg = blockIdx.x;
  int bh = wg >> 4, c = wg & 15;
  int b = bh >> 3, h = bh & 7;
  int t0 = c * 128;
  int tid = threadIdx.x;
  int lane = tid & 63, wave = tid >> 6;
  int wbase = wave * 16;
  int l15 = lane & 15, lq = lane >> 4;

  const size_t qkvbase = ((size_t)b * TSEQ + t0) * 1024 + h * 128;

  for (int it = 0; it < 2; ++it) {
    int ci = tid + it * 512;
    int t = (ci >> 4) * 2, s = ci & 15;
    bf16x8 k0 = *(const bf16x8*)(Kb + qkvbase + (size_t)t * 1024 + s * 8);
    bf16x8 k1 = *(const bf16x8*)(Kb + qkvbase + (size_t)(t + 1) * 1024 + s * 8);
    bf16x8 v0 = *(const bf16x8*)(Vb + qkvbase + (size_t)t * 1024 + s * 8);
    bf16x8 v1 = *(const bf16x8*)(Vb + qkvbase + (size_t)(t + 1) * 1024 + s * 8);
    const unsigned short* k0u = (const unsigned short*)&k0;
    const unsigned short* k1u = (const unsigned short*)&k1;
    const unsigned short* v0u = (const unsigned short*)&v0;
    const unsigned short* v1u = (const unsigned short*)&v1;
#pragma unroll
    for (int e = 0; e < 8; ++e) {
      int d = s * 8 + e;
      int off = d * 256 + (((t >> 3) ^ (d & 7) ^ ((d >> 3) & 7)) << 4) + (t & 7) * 2;
      *(unsigned int*)(KTl + off) = (unsigned)k0u[e] | ((unsigned)k1u[e] << 16);
      *(unsigned int*)(VTl + off) = (unsigned)v0u[e] | ((unsigned)v1u[e] << 16);
    }
  }
  if (wave < 4) {
    int k = wave;
    int rowg = b * TSEQ + t0 + 2 * lane;
    float m0 = mask[rowg], m1 = mask[rowg + 1];
    size_t i0 = (size_t)rowg * 32 + h * 4 + k;
    float rr0 = (m0 > 0.f) ? R[i0] : 1.f;
    float rr1 = (m1 > 0.f) ? R[i0 + 32] : 1.f;
    float incl = rr0 * rr1;
#pragma unroll
    for (int off = 1; off < 64; off <<= 1) {
      float o = __shfl_up(incl, off);
      if (lane >= off) incl *= o;
    }
    float excl = __shfl_up(incl, 1);
    if (lane == 0) excl = 1.f;
    float a0 = fmaxf(excl * rr0, 1e-25f);
    float a1 = fmaxf(a0 * rr1, 1e-25f);
    float aC = __shfl(a1, 63);
    if (lane == 63) AC[(bh * 16 + c) * 4 + k] = a1;
    bool v0 = m0 > 0.f, v1 = m1 > 0.f;
    float w0 = Wsm[i0], w1 = Wsm[i0 + 32];
    float wa0 = v0 ? w0 * a0 : 0.f;
    float wa1 = v1 ? w1 * a1 : 0.f;
    WAl[2 * lane][k] = wa0;
    WAl[2 * lane + 1][k] = wa1;
    IAl[2 * lane][k] = v0 ? 1.f / a0 : 0.f;
    IAl[2 * lane + 1][k] = v1 ? 1.f / a1 : 0.f;
    DUl[k][2 * lane] = v0 ? aC / a0 : 0.f;
    DUl[k][2 * lane + 1] = v1 ? aC / a1 : 0.f;
    WAg[i0] = wa0;
    WAg[i0 + 32] = wa1;
  }
  __syncthreads();

  bf16x8 qf[4];
#pragma unroll
  for (int ds = 0; ds < 4; ++ds)
    qf[ds] = *(const bf16x8*)(Qb + qkvbase + (size_t)(wbase + l15) * 1024 + ds * 32 + lq * 8);
  f32x4 accP[8];
#pragma unroll
  for (int jf = 0; jf < 8; ++jf) {
    f32x4 a = {};
#pragma unroll
    for (int ds = 0; ds < 4; ++ds) {
      bf16x8 kfrag = *(const bf16x8*)(Kb + qkvbase + (size_t)(jf * 16 + l15) * 1024 + ds * 32 + lq * 8);
      a = __builtin_amdgcn_mfma_f32_16x16x32_bf16(qf[ds], kfrag, a, 0, 0, 0);
    }
    accP[jf] = a;
  }

  float4 wa4[4];
#pragma unroll
  for (int jj = 0; jj < 4; ++jj)
    wa4[jj] = *(const float4*)&WAl[wbase + lq * 4 + jj][0];
#pragma unroll
  for (int jf = 0; jf < 8; ++jf) {
    float4 ia4 = *(const float4*)&IAl[jf * 16 + l15][0];
#pragma unroll
    for (int jj = 0; jj < 4; ++jj) {
      int tl = wbase + lq * 4 + jj;
      int jl = jf * 16 + l15;
      float m = 0.f;
      if (jl <= tl)
        m = wa4[jj].x * ia4.x + wa4[jj].y * ia4.y + wa4[jj].z * ia4.z + wa4[jj].w * ia4.w;
      float pv = accP[jf][jj] * m;
      int off = tl * 256 + (((jl >> 3) ^ (tl & 7)) << 4) + (jl & 7) * 2;
      *(unsigned short*)(Pl + off) = f2bf(pv);
    }
  }

  bf16x8 pf[4];
#pragma unroll
  for (int js = 0; js < 4; ++js) {
    int tl = wbase + l15;
    int slot = js * 4 + lq;
    pf[js] = *(const bf16x8*)(Pl + tl * 256 + ((slot ^ (tl & 7)) << 4));
  }
  size_t olb = (size_t)wg * 16384 + wave * 2048 + lane;
#pragma unroll
  for (int dvf = 0; dvf < 8; ++dvf) {
    f32x4 a = {};
    int dv = dvf * 16 + l15;
#pragma unroll
    for (int js = 0; js < 4; ++js) {
      int slot = js * 4 + lq;
      bf16x8 vfrag = *(const bf16x8*)(VTl + dv * 256 + KV_SLOT(slot, dv));
      a = __builtin_amdgcn_mfma_f32_16x16x32_bf16(pf[js], vfrag, a, 0, 0, 0);
    }
#pragma unroll
    for (int jj = 0; jj < 4; ++jj)
      Olb[olb + (dvf * 4 + jj) * 64] = f2bf(a[jj]);
  }

  if (c < 15) {
#pragma unroll 1
    for (int k = 0; k < 4; ++k) {
      f32x4 accU[8] = {};
#pragma unroll 1
      for (int js = 0; js < 4; ++js) {
        int dvr = wbase + l15;
        int slot = js * 4 + lq;
        bf16x8 af = *(const bf16x8*)(VTl + dvr * 256 + KV_SLOT(slot, dvr));
        int j0 = js * 32 + lq * 8;
        bf16x8 afs;
#pragma unroll
        for (int e = 0; e < 8; ++e)
          afs[e] = (__bf16)((float)af[e] * DUl[k][j0 + e]);
#pragma unroll
        for (int dkf = 0; dkf < 8; ++dkf) {
          int dk = dkf * 16 + l15;
          bf16x8 kf = *(const bf16x8*)(KTl + dk * 256 + KV_SLOT(slot, dk));
          accU[dkf] = __builtin_amdgcn_mfma_f32_16x16x32_bf16(afs, kf, accU[dkf], 0, 0, 0);
        }
      }
      size_t ub = (((size_t)bh * 16 + c) * 4 + k) * 16384 + wave * 2048 + lane;
#pragma unroll
      for (int dkf = 0; dkf < 8; ++dkf)
#pragma unroll
        for (int jj = 0; jj < 4; ++jj)
          UT[ub + (dkf * 4 + jj) * 64] = f2bf(accU[dkf][jj]);
    }
  }
}

// --- kernel B: S <- aC*S + U. Reads UT frag-linear (coalesced), writes S0T ROW-MAJOR ---
__global__ __launch_bounds__(256) void chainB_kernel(const unsigned short* __restrict__ UT,
    const float* __restrict__ AC, unsigned short* __restrict__ S0T) {
  int id = blockIdx.x * 256 + threadIdx.x;
  int q = id & 4095;
  int k = (id >> 12) & 3;
  int bh = id >> 14;
  int row = ((q >> 9) << 4) + (((q & 15) >> 2) << 2) + ((q >> 4) & 3);
  int col = (((q >> 6) & 7) << 4) + ((q & 3) << 2);
  size_t rdofs = (size_t)q * 4;
  size_t wrofs = (size_t)row * 128 + col;
  float S0 = 0.f, S1 = 0.f, S2 = 0.f, S3 = 0.f;
#pragma unroll 1
  for (int c = 0; c < 15; ++c) {
    size_t ub = (((size_t)bh * 16 + c) * 4 + k) * 16384 + rdofs;
    ushort4 u = *(const ushort4*)(UT + ub);
    float aC = AC[(bh * 16 + c) * 4 + k];
    S0 = aC * S0 + bf2f(u.x);
    S1 = aC * S1 + bf2f(u.y);
    S2 = aC * S2 + bf2f(u.z);
    S3 = aC * S3 + bf2f(u.w);
    size_t sb = (((size_t)bh * 16 + (c + 1)) * 4 + k) * 16384 + wrofs;
    ushort4 o;
    o.x = f2bf(S0); o.y = f2bf(S1); o.z = f2bf(S2); o.w = f2bf(S3);
    *(ushort4*)(S0T + sb) = o;
  }
}

// --------- kernel C: cross-chunk O += sum_k diag(w*a) Q @ S0^k (R13-fix inner loop) ---------
__global__ __launch_bounds__(512) void chunkC_kernel(const unsigned short* __restrict__ Qb,
    const unsigned short* __restrict__ S0T, const float* __restrict__ WA,
    const unsigned short* __restrict__ Olb, unsigned short* __restrict__ Ob) {
  __shared__ __align__(16) char Sl[32768];
  int wg = blockIdx.x;
  int bh = wg >> 4, c = wg & 15;
  int b = bh >> 3, h = bh & 7;
  int t0 = c * 128;
  int tid = threadIdx.x, lane = tid & 63, wave = tid >> 6;
  int l15 = lane & 15, lq = lane >> 4, wbase = wave * 16;
  size_t qbase = ((size_t)b * TSEQ + t0) * 1024 + h * 128;

  f32x4 accO[8] = {};
  if (c > 0) {
    int tl = wbase + l15;
    size_t so[4];
#pragma unroll
    for (int it = 0; it < 4; ++it) {
      int ci = tid + it * 512;
      int dv = ci >> 4, p = ci & 15;
      so[it] = (size_t)dv * 128 + (size_t)(p ^ (dv & 7)) * 8;
    }
#pragma unroll 1
    for (int k = 0; k < 4; ++k) {
      __syncthreads();
      size_t sb = (((size_t)bh * 16 + c) * 4 + k) * 16384;
      GLDS16(S0T + sb + so[0], (unsigned short*)(Sl + wave * 1024));
      GLDS16(S0T + sb + so[1], (unsigned short*)(Sl + 8192 + wave * 1024));
      GLDS16(S0T + sb + so[2], (unsigned short*)(Sl + 16384 + wave * 1024));
      GLDS16(S0T + sb + so[3], (unsigned short*)(Sl + 24576 + wave * 1024));
      asm volatile("s_waitcnt vmcnt(0)" ::: "memory");
      __syncthreads();
      float sc = WA[((size_t)b * TSEQ + t0 + tl) * 32 + h * 4 + k];
#pragma unroll 1
      for (int ds = 0; ds < 4; ++ds) {
        bf16x8 qf = *(const bf16x8*)(Qb + qbase + (size_t)tl * 1024 + ds * 32 + lq * 8);
        bf16x8 qs;
#pragma unroll
        for (int e = 0; e < 8; ++e) qs[e] = (__bf16)((float)qf[e] * sc);
#pragma unroll
        for (int dvf = 0; dvf < 8; ++dvf) {
          int dv = dvf * 16 + l15;
          int slot = ds * 4 + lq;
          bf16x8 sf = *(const bf16x8*)(Sl + dv * 256 + ((slot ^ (dv & 7)) << 4));
          accO[dvf] = __builtin_amdgcn_mfma_f32_16x16x32_bf16(qs, sf, accO[dvf], 0, 0, 0);
        }
      }
    }
  }
  size_t olb = (size_t)wg * 16384 + wave * 2048 + lane;
#pragma unroll
  for (int dvf = 0; dvf < 8; ++dvf) {
    int dv = dvf * 16 + l15;
#pragma unroll
    for (int jj = 0; jj < 4; ++jj) {
      int tl = wbase + lq * 4 + jj;
      size_t off = ((size_t)b * TSEQ + t0 + tl) * 1024 + h * 128 + dv;
      float ol = bf2f(Olb[olb + (dvf * 4 + jj) * 64]);
      Ob[off] = f2bf(accO[dvf][jj] + ol);
    }
  }
}

// ------- LayerNorm: y = P0+P1+bo+x (P bf16), then LN -> f32 out -------
__global__ __launch_bounds__(256) void ln_kernel(const unsigned short* __restrict__ Pbase,
    const float* __restrict__ bo, const float* __restrict__ xres,
    const float* __restrict__ g, const float* __restrict__ bta,
    float* __restrict__ out) {
  int row = blockIdx.x;
  int tid = threadIdx.x;
  int lane = tid & 63, wave = tid >> 6;
  __shared__ float red[8];
  size_t base = (size_t)row * 1024 + tid * 4;
  const size_t PS = (size_t)4096 * 1024;
  ushort4 a = *(const ushort4*)(Pbase + base);
  ushort4 b2 = *(const ushort4*)(Pbase + PS + base);
  float4 xv = *(const float4*)(xres + base);
  float4 bv = *(const float4*)(bo + tid * 4);
  float4 v;
  v.x = bf2f(a.x) + bf2f(b2.x) + bv.x + xv.x;
  v.y = bf2f(a.y) + bf2f(b2.y) + bv.y + xv.y;
  v.z = bf2f(a.z) + bf2f(b2.z) + bv.z + xv.z;
  v.w = bf2f(a.w) + bf2f(b2.w) + bv.w + xv.w;
  float sum = v.x + v.y + v.z + v.w;
#pragma unroll
  for (int off = 32; off > 0; off >>= 1) sum += __shfl_down(sum, off);
  if (lane == 0) red[wave] = sum;
  __syncthreads();
  float mu = (red[0] + red[1] + red[2] + red[3]) * (1.f / 1024.f);
  float4 d;
  d.x = v.x - mu; d.y = v.y - mu; d.z = v.z - mu; d.w = v.w - mu;
  float sq = d.x * d.x + d.y * d.y + d.z * d.z + d.w * d.w;
#pragma unroll
  for (int off = 32; off > 0; off >>= 1) sq += __shfl_down(sq, off);
  __syncthreads();
  if (lane == 0) red[4 + wave] = sq;
  __syncthreads();
  float var = (red[4] + red[5] + red[6] + red[7]) * (1.f / 1024.f);
  float inv = rsqrtf(var + 1e-5f);
  float4 gg = *(const float4*)(g + tid * 4);
  float4 bb4 = *(const float4*)(bta + tid * 4);
  float4 o;
  o.x = d.x * inv * gg.x + bb4.x;
  o.y = d.y * inv * gg.y + bb4.y;
  o.z = d.z * inv * gg.z + bb4.z;
  o.w = d.w * inv * gg.w + bb4.w;
  *(float4*)(out + (size_t)row * 1024 + tid * 4) = o;
}

extern "C" void kernel_launch(void* const* d_in, const int* in_sizes, int n_in,
                              void* d_out, int out_size, void* d_ws, size_t ws_size,
                              hipStream_t stream) {
  const float* x    = (const float*)d_in[0];
  const float* mask = (const float*)d_in[1];
  const float* Wq   = (const float*)d_in[2];
  const float* Wk   = (const float*)d_in[3];
  const float* Wv   = (const float*)d_in[4];
  const float* Wb   = (const float*)d_in[5];
  const float* bb   = (const float*)d_in[6];
  const float* Wm   = (const float*)d_in[7];
  const float* bm   = (const float*)d_in[8];
  const float* Wo   = (const float*)d_in[9];
  const float* bo   = (const float*)d_in[10];
  const float* base_logit = (const float*)d_in[11];
  const float* ln_g = (const float*)d_in[12];
  const float* ln_b = (const float*)d_in[13];

  char* ws = (char*)d_ws;
  const size_t MB = 1024u * 1024u;
  unsigned short* Xb    = (unsigned short*)(ws + 0);        // 8 MB
  unsigned short* Wqkvt = (unsigned short*)(ws + 8 * MB);   // 6 MB
  unsigned short* Wto   = (unsigned short*)(ws + 14 * MB);  // 2 MB
  float* Rf  = (float*)(ws + 16 * MB);
  float* Wsf = (float*)(ws + 16 * MB + 512 * 1024);
  float* WAf = (float*)(ws + 17 * MB);
  float* ACf = (float*)(ws + 18 * MB);
  float* Wtf = (float*)(ws + 18 * MB + 768 * 1024);
  unsigned short* Qb  = (unsigned short*)(ws + 19 * MB);    // 8 MB
  unsigned short* Kb  = (unsigned short*)(ws + 27 * MB);    // 8 MB
  unsigned short* Vb  = (unsigned short*)(ws + 35 * MB);    // 8 MB
  unsigned short* Olb = (unsigned short*)(ws + 43 * MB);    // 8 MB bf16 (frag-linear)
  unsigned short* Ob  = (unsigned short*)(ws + 51 * MB);    // 8 MB
  unsigned short* UTb = (unsigned short*)(ws + 59 * MB);    // 32 MB (frag-linear)
  unsigned short* S0T = (unsigned short*)(ws + 91 * MB);    // 32 MB (row-major)
  unsigned short* Pp = (unsigned short*)(ws + 59 * MB);     // 2x8 MB bf16 partials (UTb dead)
  if (ws_size < 131 * MB) return;

  dim3 tb(32, 8), tg(32, 32, 5);
  transpose_all_kernel<<<tg, tb, 0, stream>>>(Wq, Wk, Wv, Wo, Wb, Wm, Wqkvt, Wto, Wtf);

  rw8_kernel<<<512, 256, 0, stream>>>(x, Wtf, bb, bm, base_logit, Rf, Wsf, Xb);

  dim3 gqkv(24, 32);
  gemm_pipe_kernel<0><<<gqkv, 256, 0, stream>>>(Xb, Wqkvt, Qb, Kb, Vb, nullptr);

  chunkA_kernel<<<256, 512, 0, stream>>>(Qb, Kb, Vb, Rf, Wsf, mask, WAf, ACf, Olb, UTb);
  chainB_kernel<<<1024, 256, 0, stream>>>(UTb, ACf, S0T);
  chunkC_kernel<<<256, 512, 0, stream>>>(Qb, S0T, WAf, Olb, Ob);

  dim3 gwo(8, 32, 2);
  gemm_pipe_kernel<1><<<gwo, 256, 0, stream>>>(Ob, Wto, nullptr, nullptr, nullptr, Pp);

  ln_kernel<<<4096, 256, 0, stream>>>(Pp, bo, x, ln_g, ln_b, (float*)d_out);
}